// Round 6
// baseline (178.675 us; speedup 1.0000x reference)
//
#include <hip/hip_runtime.h>

#define C 96
#define TB 64           // tile/bucket width (nodes) — bucket == layer tile
#define EB 2048         // edges per sort item
#define NBP 1024        // padded bucket count for sort scan (NB=782 <= 1024)
#define LCAP 2048       // per-tile local csr capacity (mean 1024, >±9 sigma)
typedef unsigned char u8;
typedef unsigned short u16;
typedef unsigned int u32;
typedef __attribute__((ext_vector_type(8))) short short8;
typedef __attribute__((ext_vector_type(4))) float floatx4;
typedef __attribute__((ext_vector_type(2))) float floatx2;

__device__ inline u16 f2bf(float f) {
    union { float f; u32 u; } v; v.f = f;
    u32 r = v.u + 0x7fff + ((v.u >> 16) & 1);   // RNE
    return (u16)(r >> 16);
}
__device__ inline u32 pk4_fp8(float a, float b, float c, float d) {
    u32 w = 0;
    w = __builtin_amdgcn_cvt_pk_fp8_f32(a, b, w, false);
    w = __builtin_amdgcn_cvt_pk_fp8_f32(c, d, w, true);
    return w;
}
__device__ inline u8 f2fp8(float a) {
    return (u8)(__builtin_amdgcn_cvt_pk_fp8_f32(a, a, 0, false) & 0xff);
}

// ---------------------------------------------------------------------------
// sort: blocks [0,DB) counting-sort 2048 edges into 782 dst-buckets (64-wide)
// in LDS; flush private per-item stage region + PACKED transposed
// per-(bucket,item) descriptor table (cnt<<16 | off — both < 2048).
// Blocks [DB,DB+CX): x -> bf16+fp8. Last 4: W -> bf16^T.
__global__ __launch_bounds__(256) void sort_kernel(const int* __restrict__ src,
                                                   const int* __restrict__ dst,
                                                   u32* __restrict__ tabT,
                                                   u32* __restrict__ stage,
                                                   int E, int DB, int NB,
                                                   const float* __restrict__ x,
                                                   u16* __restrict__ xb,
                                                   u8* __restrict__ xf8, int n16, int CX,
                                                   const float* W0, const float* W1,
                                                   const float* W2, const float* W3,
                                                   u16* T0, u16* T1, u16* T2, u16* T3) {
    int bid = blockIdx.x;
    int t = threadIdx.x;
    if (bid >= DB) {
        int cc = bid - DB;
        if (cc < CX) {
            int i = cc * 256 + t;
            if (i >= n16) return;
            const float4* p = (const float4*)x + (size_t)i * 4;
            float4 a = p[0], b = p[1], c = p[2], d = p[3];
            short8 o0, o1;
            o0[0] = (short)f2bf(a.x); o0[1] = (short)f2bf(a.y);
            o0[2] = (short)f2bf(a.z); o0[3] = (short)f2bf(a.w);
            o0[4] = (short)f2bf(b.x); o0[5] = (short)f2bf(b.y);
            o0[6] = (short)f2bf(b.z); o0[7] = (short)f2bf(b.w);
            o1[0] = (short)f2bf(c.x); o1[1] = (short)f2bf(c.y);
            o1[2] = (short)f2bf(c.z); o1[3] = (short)f2bf(c.w);
            o1[4] = (short)f2bf(d.x); o1[5] = (short)f2bf(d.y);
            o1[6] = (short)f2bf(d.z); o1[7] = (short)f2bf(d.w);
            *(short8*)(xb + (size_t)i * 16) = o0;
            *(short8*)(xb + (size_t)i * 16 + 8) = o1;
            uint4 f8;
            f8.x = pk4_fp8(a.x, a.y, a.z, a.w);
            f8.y = pk4_fp8(b.x, b.y, b.z, b.w);
            f8.z = pk4_fp8(c.x, c.y, c.z, c.w);
            f8.w = pk4_fp8(d.x, d.y, d.z, d.w);
            *(uint4*)(xf8 + (size_t)i * 16) = f8;
        } else {
            int w = cc - CX;
            const float* W = w == 0 ? W0 : w == 1 ? W1 : w == 2 ? W2 : W3;
            u16* T = w == 0 ? T0 : w == 1 ? T1 : w == 2 ? T2 : T3;
            for (int i = t; i < C * C; i += 256) {
                int k = i / C, n = i - k * C;
                T[n * C + k] = f2bf(W[i]);
            }
        }
        return;
    }

    __shared__ u32 s_word[EB];
    __shared__ int s_cnt[NBP];
    __shared__ int s_off[NBP];
    __shared__ int s_scan[256];
    int e0 = bid * EB;
    int cnt_here = min(EB, E - e0);

    for (int i = t; i < NBP; i += 256) s_cnt[i] = 0;
    __syncthreads();

    int my_src[EB / 256], my_dl[EB / 256], my_b[EB / 256], my_rank[EB / 256];
    int nmine = 0;
#pragma unroll
    for (int k = 0; k < EB / 256; k++) {
        int i = t + k * 256;
        if (i < cnt_here) {
            int s = src[e0 + i], d = dst[e0 + i];
            int b = d >> 6;                  // 64-wide buckets
            my_src[nmine] = s;
            my_dl[nmine] = d & (TB - 1);
            my_b[nmine] = b;
            my_rank[nmine] = atomicAdd(&s_cnt[b], 1);
            nmine++;
        }
    }
    __syncthreads();

    // exclusive scan over NBP=1024 buckets: 4 per thread + 256-ladder
    int b4 = t * 4;
    int v0 = s_cnt[b4], v1 = s_cnt[b4 + 1], v2 = s_cnt[b4 + 2], v3 = s_cnt[b4 + 3];
    int lsum = v0 + v1 + v2 + v3;
    s_scan[t] = lsum;
    __syncthreads();
    for (int off = 1; off < 256; off <<= 1) {
        int x2 = (t >= off) ? s_scan[t - off] : 0;
        __syncthreads();
        s_scan[t] += x2;
        __syncthreads();
    }
    int excl = s_scan[t] - lsum;
    s_off[b4] = excl;
    s_off[b4 + 1] = excl + v0;
    s_off[b4 + 2] = excl + v0 + v1;
    s_off[b4 + 3] = excl + v0 + v1 + v2;
    __syncthreads();

    // packed transposed table: column `bid` of each bucket row
    for (int b = t; b < NB; b += 256)
        tabT[(size_t)b * DB + bid] = ((u32)s_cnt[b] << 16) | (u32)s_off[b];

    for (int k = 0; k < nmine; k++) {
        int slot = s_off[my_b[k]] + my_rank[k];
        s_word[slot] = ((u32)my_dl[k] << 16) | (u32)my_src[k];
    }
    __syncthreads();

    for (int i = t; i < cnt_here; i += 256) stage[(size_t)bid * EB + i] = s_word[i];
}

// ---------------------------------------------------------------------------
// Fused layer: Y = (RELU?)(mean_agg(X)@WA + X@WR + BIAS) for 64 nodes/block.
// Build: single global walk (thread-private LDS segments via 256-scan) ->
// LDS re-scatter to per-node lists. Gather: fp8, aligned slices, 4-edge
// pipeline (12 loads in flight/wave) at 6 waves/EU — in-flight ~288/CU.
// MFMA + coalesced epilogue unchanged.
template <bool RELU, bool WF8, typename OT>
__global__ __launch_bounds__(256, 6) void layer_kernel(const u16* __restrict__ Xbf,
                                                       const u8* __restrict__ Xf8,
                                                       const u32* __restrict__ tabT,
                                                       const u32* __restrict__ stage,
                                                       const u16* __restrict__ WTA,
                                                       const u16* __restrict__ WTR,
                                                       const float* __restrict__ BIAS,
                                                       OT* __restrict__ Y,
                                                       u8* __restrict__ Yf8, int n, int DB) {
    __shared__ __align__(16) u16 sA[64 * 104];   // gather tile / raw union / out staging
    __shared__ u16 lcsr[LCAP];
    __shared__ int s_dg[TB];        // per-node degree
    __shared__ int s_off64[TB];     // per-node list start
    __shared__ int s_cur64[TB];     // scan scratch / scatter cursor
    __shared__ int s_perm[TB];
    __shared__ int ssum[256];
    u32* raw = (u32*)sA;            // arrival-order edge words (dead before sA use)
    const int t = threadIdx.x;
    const int b = blockIdx.x;       // tile id == bucket id
    const int row0 = b * 64;
    const u32* tab_b = tabT + (size_t)b * DB;

    // ---- build a: descriptors + segment scan + single global walk ----
    for (int i = t; i < TB; i += 256) s_dg[i] = 0;
    u32 p0 = (t < DB) ? tab_b[t] : 0;
    u32 p1 = (t + 256 < DB) ? tab_b[t + 256] : 0;
    int l0 = p0 >> 16, o0 = p0 & 0xffff;
    int l1 = p1 >> 16, o1 = p1 & 0xffff;
    int tot = l0 + l1;
    ssum[t] = tot;
    __syncthreads();
    for (int off = 1; off < 256; off <<= 1) {
        int x2 = (t >= off) ? ssum[t - off] : 0;
        __syncthreads();
        ssum[t] += x2;
        __syncthreads();
    }
    const int seg0 = ssum[t] - tot;
    int pos = seg0;
    {
        const u32* run = stage + (size_t)t * EB + o0;
        for (int j = 0; j < l0; j++) {
            u32 w = run[j];
            if (pos < LCAP) { raw[pos++] = w; atomicAdd(&s_dg[w >> 16], 1); }
        }
        const u32* run2 = stage + ((size_t)t + 256) * EB + o1;
        for (int j = 0; j < l1; j++) {
            u32 w = run2[j];
            if (pos < LCAP) { raw[pos++] = w; atomicAdd(&s_dg[w >> 16], 1); }
        }
    }
    const int stored = pos - seg0;
    __syncthreads();

    // ---- build b: 64-wide exclusive scan of degrees ----
    int dv = (t < TB) ? s_dg[t] : 0;
    if (t < TB) s_cur64[t] = dv;
    __syncthreads();
    for (int off = 1; off < TB; off <<= 1) {
        int x2 = (t >= off && t < TB) ? s_cur64[t - off] : 0;
        __syncthreads();
        if (t < TB) s_cur64[t] += x2;
        __syncthreads();
    }
    if (t < TB) s_off64[t] = s_cur64[t] - dv;
    __syncthreads();
    if (t < TB) s_cur64[t] = s_off64[t];
    __syncthreads();

    // ---- build c: LDS re-scatter raw -> per-node lists ----
    for (int k = 0; k < stored; k++) {
        u32 w = raw[seg0 + k];
        int p = atomicAdd(&s_cur64[w >> 16], 1);
        lcsr[p] = (u16)(w & 0xffffu);
    }
    __syncthreads();

    // ---- degree-rank permutation ----
    if (t < 64) {
        int di = s_dg[t];
        int r = 0;
#pragma unroll 8
        for (int j = 0; j < 64; j++) {
            int dj = s_dg[j];
            r += (dj < di) || (dj == di && j < t);
        }
        s_perm[r] = t;
    }
    __syncthreads();

    // ---- gather: fp8 mean (4 lanes/node, 24ch each, 4-edge pipeline) ----
    // lane q owns channels [16q,16q+16) (acc[0..15]) and [64+8q,72+8q) (acc[16..23])
    {
        int nl = s_perm[t >> 2];
        int q = t & 3;
        float acc[24];
#pragma unroll
        for (int i = 0; i < 24; i++) acc[i] = 0.f;
        int d = s_dg[nl];
        int start = s_off64[nl];
        const int off4 = q * 16;        // dwordx4 slice offset
        const int off2 = 64 + q * 8;    // dwordx2 slice offset

#define CONSUME(va, vb)                                                     \
        do {                                                                \
            u32 ws[6] = {(va).x, (va).y, (va).z, (va).w, (vb).x, (vb).y};   \
            _Pragma("unroll")                                               \
            for (int i = 0; i < 6; i++) {                                   \
                floatx2 lo = __builtin_amdgcn_cvt_pk_f32_fp8(ws[i], false); \
                floatx2 hi = __builtin_amdgcn_cvt_pk_f32_fp8(ws[i], true);  \
                acc[4 * i]     += lo[0];                                    \
                acc[4 * i + 1] += lo[1];                                    \
                acc[4 * i + 2] += hi[0];                                    \
                acc[4 * i + 3] += hi[1];                                    \
            }                                                               \
        } while (0)

        int j = 0;
        if (d >= 4) {
            int si[4];
#pragma unroll
            for (int k = 0; k < 4; k++) si[k] = lcsr[start + k];
            for (; j + 8 <= d; j += 4) {
                uint4 va[4];
                uint2 vb[4];
#pragma unroll
                for (int k = 0; k < 4; k++) {
                    const u8* p = Xf8 + (size_t)si[k] * 96;
                    va[k] = *(const uint4*)(p + off4);
                    vb[k] = *(const uint2*)(p + off2);
                }
                int sn[4];    // prefetch next quad's indices before consuming
#pragma unroll
                for (int k = 0; k < 4; k++) sn[k] = lcsr[start + j + 4 + k];
#pragma unroll
                for (int k = 0; k < 4; k++) CONSUME(va[k], vb[k]);
#pragma unroll
                for (int k = 0; k < 4; k++) si[k] = sn[k];
            }
            {   // drain the in-flight quad
                uint4 va[4];
                uint2 vb[4];
#pragma unroll
                for (int k = 0; k < 4; k++) {
                    const u8* p = Xf8 + (size_t)si[k] * 96;
                    va[k] = *(const uint4*)(p + off4);
                    vb[k] = *(const uint2*)(p + off2);
                }
#pragma unroll
                for (int k = 0; k < 4; k++) CONSUME(va[k], vb[k]);
                j += 4;
            }
        }
        for (; j < d; j++) {
            const u8* p = Xf8 + (size_t)lcsr[start + j] * 96;
            uint4 va = *(const uint4*)(p + off4);
            uint2 vb = *(const uint2*)(p + off2);
            CONSUME(va, vb);
        }
#undef CONSUME

        float inv = 1.0f / fmaxf((float)d, 1.0f);
        u16* dl = sA + nl * 104;
        short8 o0v, o1v, o2v;
#pragma unroll
        for (int i = 0; i < 8; i++) {
            o0v[i] = (short)f2bf(acc[i] * inv);
            o1v[i] = (short)f2bf(acc[8 + i] * inv);
            o2v[i] = (short)f2bf(acc[16 + i] * inv);
        }
        *(short8*)(dl + q * 16) = o0v;          // channels 16q..16q+7
        *(short8*)(dl + q * 16 + 8) = o1v;      // channels 16q+8..16q+15
        *(short8*)(dl + 64 + q * 8) = o2v;      // channels 64+8q..64+8q+7
    }
    __syncthreads();

    // ---- dual MFMA GEMM ----
    const int lane = t & 63;
    const int w = t >> 6;
    const int quad = lane >> 4;
    const int l16 = lane & 15;
    const int r0 = row0 + w * 16;

    floatx4 acc6[6];
#pragma unroll
    for (int i = 0; i < 6; i++) acc6[i] = (floatx4){0.f, 0.f, 0.f, 0.f};

    {   // A-path: aggregated tile from LDS
        const u16* Ap = sA + (w * 16 + l16) * 104 + quad * 8;
        const u16* Wp = WTA + l16 * C + quad * 8;
#pragma unroll
        for (int ks = 0; ks < 3; ks++) {
            short8 a = *(const short8*)(Ap + ks * 32);
#pragma unroll
            for (int nt = 0; nt < 6; nt++) {
                short8 bb = *(const short8*)(Wp + nt * 16 * C + ks * 32);
                acc6[nt] = __builtin_amdgcn_mfma_f32_16x16x32_bf16(a, bb, acc6[nt], 0, 0, 0);
            }
        }
    }
    {   // Root path: own rows from global (bf16)
        int arow = r0 + l16;
        if (arow >= n) arow = n - 1;
        const u16* Xp = Xbf + (size_t)arow * C + quad * 8;
        const u16* Wp = WTR + l16 * C + quad * 8;
#pragma unroll
        for (int ks = 0; ks < 3; ks++) {
            short8 a = *(const short8*)(Xp + ks * 32);
#pragma unroll
            for (int nt = 0; nt < 6; nt++) {
                short8 bb = *(const short8*)(Wp + nt * 16 * C + ks * 32);
                acc6[nt] = __builtin_amdgcn_mfma_f32_16x16x32_bf16(a, bb, acc6[nt], 0, 0, 0);
            }
        }
    }

    // bias + relu in registers
#pragma unroll
    for (int nt = 0; nt < 6; nt++) {
        float bv = BIAS[nt * 16 + l16];
#pragma unroll
        for (int r = 0; r < 4; r++) {
            float v = acc6[nt][r] + bv;
            if (RELU) v = fmaxf(v, 0.f);
            acc6[nt][r] = v;
        }
    }
    __syncthreads();   // all sA (A-path) reads complete; safe to reuse

    const int nrow = min(64, n - row0);
    const int lr = w * 16 + quad * 4;          // this lane's tile rows lr..lr+3

    if constexpr (sizeof(OT) == 2) {
        // ---- bf16 output: stage 64x96 u16 (12 KB), write contiguous ----
        u16* so = sA;
#pragma unroll
        for (int nt = 0; nt < 6; nt++)
#pragma unroll
            for (int r = 0; r < 4; r++)
                so[(lr + r) * 96 + nt * 16 + l16] = f2bf(acc6[nt][r]);
        __syncthreads();
        {
            char* dstp = (char*)Y + (size_t)row0 * 192;
            int nbytes = nrow * 192;
            for (int ofs = t * 16; ofs < nbytes; ofs += 4096)
                *(uint4*)(dstp + ofs) = *(const uint4*)((const char*)sA + ofs);
        }
        if constexpr (WF8) {
            __syncthreads();
            u8* so8 = (u8*)sA;
#pragma unroll
            for (int nt = 0; nt < 6; nt++)
#pragma unroll
                for (int r = 0; r < 4; r++)
                    so8[(lr + r) * 96 + nt * 16 + l16] = f2fp8(acc6[nt][r]);
            __syncthreads();
            char* dst8 = (char*)Yf8 + (size_t)row0 * 96;
            int nb8 = nrow * 96;
            for (int ofs = t * 16; ofs < nb8; ofs += 4096)
                *(uint4*)(dst8 + ofs) = *(const uint4*)((const char*)sA + ofs);
        }
    } else {
        // ---- fp32 output: two 32-row halves (12 KB each) ----
        float* sof = (float*)sA;
#pragma unroll
        for (int half = 0; half < 2; half++) {
            if (half) __syncthreads();
            if ((w >> 1) == half) {
#pragma unroll
                for (int nt = 0; nt < 6; nt++)
#pragma unroll
                    for (int r = 0; r < 4; r++)
                        sof[((w & 1) * 16 + quad * 4 + r) * 96 + nt * 16 + l16] = acc6[nt][r];
            }
            __syncthreads();
            int rbase = row0 + half * 32;
            int nr = n - rbase;
            nr = nr < 0 ? 0 : (nr > 32 ? 32 : nr);
            char* dstp = (char*)Y + (size_t)rbase * 384;
            int nbytes = nr * 384;
            for (int ofs = t * 16; ofs < nbytes; ofs += 4096)
                *(uint4*)(dstp + ofs) = *(const uint4*)((const char*)sA + ofs);
        }
    }
}

// ---------------------------------------------------------------------------
extern "C" void kernel_launch(void* const* d_in, const int* in_sizes, int n_in,
                              void* d_out, int out_size, void* d_ws, size_t ws_size,
                              hipStream_t stream) {
    const float* x   = (const float*)d_in[0];
    const int*   ei  = (const int*)d_in[1];
    const float* W1  = (const float*)d_in[2];
    const float* Wr1 = (const float*)d_in[3];
    const float* b1  = (const float*)d_in[4];
    const float* W2  = (const float*)d_in[5];
    const float* Wr2 = (const float*)d_in[6];
    const float* b2  = (const float*)d_in[7];
    float* out = (float*)d_out;

    const int N = in_sizes[0] / C;      // 50000
    const int E = in_sizes[1] / 2;      // 800000
    const int* src = ei;
    const int* dst = ei + E;

    const int DB   = (E + EB - 1) / EB;                 // 391
    const int NB   = (N + TB - 1) / TB;                 // 782
    const int n16  = N * C / 16;
    const int CX   = (n16 + 255) / 256;                 // 1172
    const size_t NBDB = ((size_t)NB * DB + 3) & ~(size_t)3;   // 16B-pad

    // Workspace layout (16B alignment for vector sections)
    u32*  tabT = (u32*)d_ws;                             // NB*DB packed cnt|off
    u32*  stage = tabT + NBDB;                           // DB*EB
    u16*  xb   = (u16*)(stage + (size_t)DB * EB);        // N*C bf16
    u16*  h1b  = xb + (size_t)N * C;                     // N*C bf16
    u16*  wt   = h1b + (size_t)N * C;                    // 4*C*C bf16
    u16 *wt1 = wt, *wtr1 = wt + C * C, *wt2 = wt + 2 * C * C, *wtr2 = wt + 3 * C * C;
    u8*   xf8  = (u8*)(wt + 4 * C * C);                  // N*96 fp8
    u8*   h1f8 = xf8 + (size_t)N * 96;                   // N*96 fp8

    sort_kernel<<<DB + CX + 4, 256, 0, stream>>>(src, dst, tabT, stage,
                                                 E, DB, NB,
                                                 x, xb, xf8, n16, CX,
                                                 W1, Wr1, W2, Wr2, wt1, wtr1, wt2, wtr2);

    layer_kernel<true, true, u16><<<NB, 256, 0, stream>>>(
        xb, xf8, tabT, stage, wt1, wtr1, b1, h1b, h1f8, N, DB);
    layer_kernel<false, false, float><<<NB, 256, 0, stream>>>(
        h1b, h1f8, tabT, stage, wt2, wtr2, b2, out, h1f8, N, DB);
}

// Round 7
// 164.037 us; speedup vs baseline: 1.0892x; 1.0892x over previous
//
#include <hip/hip_runtime.h>

#define C 96
#define TB 64           // tile/bucket width (nodes) — bucket == layer tile
#define EB 2048         // edges per sort item
#define NBP 1024        // padded bucket count for sort scan (NB=782 <= 1024)
#define LCAP 2048       // per-tile local csr capacity (mean 1024, >±9 sigma)
#define F8S 128         // fp8 row stride (one cache line; 96 data + 32 pad)
typedef unsigned char u8;
typedef unsigned short u16;
typedef unsigned int u32;
typedef __attribute__((ext_vector_type(8))) short short8;
typedef __attribute__((ext_vector_type(4))) float floatx4;
typedef __attribute__((ext_vector_type(2))) float floatx2;

__device__ inline u16 f2bf(float f) {
    union { float f; u32 u; } v; v.f = f;
    u32 r = v.u + 0x7fff + ((v.u >> 16) & 1);   // RNE
    return (u16)(r >> 16);
}
__device__ inline u32 pk4_fp8(float a, float b, float c, float d) {
    u32 w = 0;
    w = __builtin_amdgcn_cvt_pk_fp8_f32(a, b, w, false);
    w = __builtin_amdgcn_cvt_pk_fp8_f32(c, d, w, true);
    return w;
}
__device__ inline u8 f2fp8(float a) {
    return (u8)(__builtin_amdgcn_cvt_pk_fp8_f32(a, a, 0, false) & 0xff);
}

// ---------------------------------------------------------------------------
// sort: blocks [0,DB) counting-sort 2048 edges into 782 dst-buckets (64-wide)
// in LDS; flush private per-item stage region + PACKED transposed
// per-(bucket,item) descriptor table (cnt<<16 | off — both < 2048).
// Blocks [DB,DB+CX): x -> bf16 + fp8 (fp8 rows PADDED to 128 B = 1 line).
// Last 4: W -> bf16^T.
__global__ __launch_bounds__(256) void sort_kernel(const int* __restrict__ src,
                                                   const int* __restrict__ dst,
                                                   u32* __restrict__ tabT,
                                                   u32* __restrict__ stage,
                                                   int E, int DB, int NB,
                                                   const float* __restrict__ x,
                                                   u16* __restrict__ xb,
                                                   u8* __restrict__ xf8, int n16, int CX,
                                                   const float* W0, const float* W1,
                                                   const float* W2, const float* W3,
                                                   u16* T0, u16* T1, u16* T2, u16* T3) {
    int bid = blockIdx.x;
    int t = threadIdx.x;
    if (bid >= DB) {
        int cc = bid - DB;
        if (cc < CX) {
            int i = cc * 256 + t;
            if (i >= n16) return;
            const float4* p = (const float4*)x + (size_t)i * 4;
            float4 a = p[0], b = p[1], c = p[2], d = p[3];
            short8 o0, o1;
            o0[0] = (short)f2bf(a.x); o0[1] = (short)f2bf(a.y);
            o0[2] = (short)f2bf(a.z); o0[3] = (short)f2bf(a.w);
            o0[4] = (short)f2bf(b.x); o0[5] = (short)f2bf(b.y);
            o0[6] = (short)f2bf(b.z); o0[7] = (short)f2bf(b.w);
            o1[0] = (short)f2bf(c.x); o1[1] = (short)f2bf(c.y);
            o1[2] = (short)f2bf(c.z); o1[3] = (short)f2bf(c.w);
            o1[4] = (short)f2bf(d.x); o1[5] = (short)f2bf(d.y);
            o1[6] = (short)f2bf(d.z); o1[7] = (short)f2bf(d.w);
            *(short8*)(xb + (size_t)i * 16) = o0;
            *(short8*)(xb + (size_t)i * 16 + 8) = o1;
            uint4 f8;
            f8.x = pk4_fp8(a.x, a.y, a.z, a.w);
            f8.y = pk4_fp8(b.x, b.y, b.z, b.w);
            f8.z = pk4_fp8(c.x, c.y, c.z, c.w);
            f8.w = pk4_fp8(d.x, d.y, d.z, d.w);
            int node = i / 6, slice = i - node * 6;     // 6 x 16B slices per row
            *(uint4*)(xf8 + (size_t)node * F8S + slice * 16) = f8;
        } else {
            int w = cc - CX;
            const float* W = w == 0 ? W0 : w == 1 ? W1 : w == 2 ? W2 : W3;
            u16* T = w == 0 ? T0 : w == 1 ? T1 : w == 2 ? T2 : T3;
            for (int i = t; i < C * C; i += 256) {
                int k = i / C, n = i - k * C;
                T[n * C + k] = f2bf(W[i]);
            }
        }
        return;
    }

    __shared__ u32 s_word[EB];
    __shared__ int s_cnt[NBP];
    __shared__ int s_off[NBP];
    __shared__ int s_scan[256];
    int e0 = bid * EB;
    int cnt_here = min(EB, E - e0);

    for (int i = t; i < NBP; i += 256) s_cnt[i] = 0;
    __syncthreads();

    int my_src[EB / 256], my_dl[EB / 256], my_b[EB / 256], my_rank[EB / 256];
    int nmine = 0;
#pragma unroll
    for (int k = 0; k < EB / 256; k++) {
        int i = t + k * 256;
        if (i < cnt_here) {
            int s = src[e0 + i], d = dst[e0 + i];
            int b = d >> 6;                  // 64-wide buckets
            my_src[nmine] = s;
            my_dl[nmine] = d & (TB - 1);
            my_b[nmine] = b;
            my_rank[nmine] = atomicAdd(&s_cnt[b], 1);
            nmine++;
        }
    }
    __syncthreads();

    // exclusive scan over NBP=1024 buckets: 4 per thread + 256-ladder
    int b4 = t * 4;
    int v0 = s_cnt[b4], v1 = s_cnt[b4 + 1], v2 = s_cnt[b4 + 2], v3 = s_cnt[b4 + 3];
    int lsum = v0 + v1 + v2 + v3;
    s_scan[t] = lsum;
    __syncthreads();
    for (int off = 1; off < 256; off <<= 1) {
        int x2 = (t >= off) ? s_scan[t - off] : 0;
        __syncthreads();
        s_scan[t] += x2;
        __syncthreads();
    }
    int excl = s_scan[t] - lsum;
    s_off[b4] = excl;
    s_off[b4 + 1] = excl + v0;
    s_off[b4 + 2] = excl + v0 + v1;
    s_off[b4 + 3] = excl + v0 + v1 + v2;
    __syncthreads();

    // packed transposed table: column `bid` of each bucket row
    for (int b = t; b < NB; b += 256)
        tabT[(size_t)b * DB + bid] = ((u32)s_cnt[b] << 16) | (u32)s_off[b];

    for (int k = 0; k < nmine; k++) {
        int slot = s_off[my_b[k]] + my_rank[k];
        s_word[slot] = ((u32)my_dl[k] << 16) | (u32)my_src[k];
    }
    __syncthreads();

    for (int i = t; i < cnt_here; i += 256) stage[(size_t)bid * EB + i] = s_word[i];
}

// ---------------------------------------------------------------------------
// Fused layer: Y = (RELU?)(mean_agg(X)@WA + X@WR + BIAS) for 64 nodes/block.
// Build: single global walk (thread-private LDS segments via 256-scan) ->
// LDS re-scatter to per-node lists. Gather: fp8 from 128B-padded rows
// (1 cache line/edge), 4-edge pipeline; launch_bounds(256,4) gives the
// 128-VGPR budget the pipeline's live set needs (R6's bound-6 squeezed the
// compiler into serializing the loads — VGPR_Count was 40).
template <bool RELU, bool WF8, typename OT>
__global__ __launch_bounds__(256, 4) void layer_kernel(const u16* __restrict__ Xbf,
                                                       const u8* __restrict__ Xf8,
                                                       const u32* __restrict__ tabT,
                                                       const u32* __restrict__ stage,
                                                       const u16* __restrict__ WTA,
                                                       const u16* __restrict__ WTR,
                                                       const float* __restrict__ BIAS,
                                                       OT* __restrict__ Y,
                                                       u8* __restrict__ Yf8, int n, int DB) {
    __shared__ __align__(16) u16 sA[64 * 104];   // gather tile / raw union / out staging
    __shared__ u16 lcsr[LCAP];
    __shared__ int s_dg[TB];        // per-node degree
    __shared__ int s_off64[TB];     // per-node list start
    __shared__ int s_cur64[TB];     // scan scratch / scatter cursor
    __shared__ int s_perm[TB];
    __shared__ int ssum[256];
    u32* raw = (u32*)sA;            // arrival-order edge words (dead before sA use)
    const int t = threadIdx.x;
    const int b = blockIdx.x;       // tile id == bucket id
    const int row0 = b * 64;
    const u32* tab_b = tabT + (size_t)b * DB;

    // ---- build a: descriptors + segment scan + single global walk ----
    for (int i = t; i < TB; i += 256) s_dg[i] = 0;
    u32 p0 = (t < DB) ? tab_b[t] : 0;
    u32 p1 = (t + 256 < DB) ? tab_b[t + 256] : 0;
    int l0 = p0 >> 16, o0 = p0 & 0xffff;
    int l1 = p1 >> 16, o1 = p1 & 0xffff;
    int tot = l0 + l1;
    ssum[t] = tot;
    __syncthreads();
    for (int off = 1; off < 256; off <<= 1) {
        int x2 = (t >= off) ? ssum[t - off] : 0;
        __syncthreads();
        ssum[t] += x2;
        __syncthreads();
    }
    const int seg0 = ssum[t] - tot;
    int pos = seg0;
    {
        const u32* run = stage + (size_t)t * EB + o0;
        for (int j = 0; j < l0; j++) {
            u32 w = run[j];
            if (pos < LCAP) { raw[pos++] = w; atomicAdd(&s_dg[w >> 16], 1); }
        }
        const u32* run2 = stage + ((size_t)t + 256) * EB + o1;
        for (int j = 0; j < l1; j++) {
            u32 w = run2[j];
            if (pos < LCAP) { raw[pos++] = w; atomicAdd(&s_dg[w >> 16], 1); }
        }
    }
    const int stored = pos - seg0;
    __syncthreads();

    // ---- build b: 64-wide exclusive scan of degrees ----
    int dv = (t < TB) ? s_dg[t] : 0;
    if (t < TB) s_cur64[t] = dv;
    __syncthreads();
    for (int off = 1; off < TB; off <<= 1) {
        int x2 = (t >= off && t < TB) ? s_cur64[t - off] : 0;
        __syncthreads();
        if (t < TB) s_cur64[t] += x2;
        __syncthreads();
    }
    if (t < TB) s_off64[t] = s_cur64[t] - dv;
    __syncthreads();
    if (t < TB) s_cur64[t] = s_off64[t];
    __syncthreads();

    // ---- build c: LDS re-scatter raw -> per-node lists ----
    for (int k = 0; k < stored; k++) {
        u32 w = raw[seg0 + k];
        int p = atomicAdd(&s_cur64[w >> 16], 1);
        lcsr[p] = (u16)(w & 0xffffu);
    }
    __syncthreads();

    // ---- degree-rank permutation ----
    if (t < 64) {
        int di = s_dg[t];
        int r = 0;
#pragma unroll 8
        for (int j = 0; j < 64; j++) {
            int dj = s_dg[j];
            r += (dj < di) || (dj == di && j < t);
        }
        s_perm[r] = t;
    }
    __syncthreads();

    // ---- gather: fp8 mean (4 lanes/node, 24ch each, 4-edge pipeline) ----
    // lane q owns channels [16q,16q+16) (acc[0..15]) and [64+8q,72+8q) (acc[16..23])
    {
        int nl = s_perm[t >> 2];
        int q = t & 3;
        float acc[24];
#pragma unroll
        for (int i = 0; i < 24; i++) acc[i] = 0.f;
        int d = s_dg[nl];
        int start = s_off64[nl];
        const int off4 = q * 16;        // dwordx4 slice offset
        const int off2 = 64 + q * 8;    // dwordx2 slice offset

#define CONSUME(va, vb)                                                     \
        do {                                                                \
            u32 ws[6] = {(va).x, (va).y, (va).z, (va).w, (vb).x, (vb).y};   \
            _Pragma("unroll")                                               \
            for (int i = 0; i < 6; i++) {                                   \
                floatx2 lo = __builtin_amdgcn_cvt_pk_f32_fp8(ws[i], false); \
                floatx2 hi = __builtin_amdgcn_cvt_pk_f32_fp8(ws[i], true);  \
                acc[4 * i]     += lo[0];                                    \
                acc[4 * i + 1] += lo[1];                                    \
                acc[4 * i + 2] += hi[0];                                    \
                acc[4 * i + 3] += hi[1];                                    \
            }                                                               \
        } while (0)

        int j = 0;
        if (d >= 4) {
            int si[4];
#pragma unroll
            for (int k = 0; k < 4; k++) si[k] = lcsr[start + k];
            for (; j + 8 <= d; j += 4) {
                uint4 va[4];
                uint2 vb[4];
#pragma unroll
                for (int k = 0; k < 4; k++) {
                    const u8* p = Xf8 + ((size_t)si[k] << 7);
                    va[k] = *(const uint4*)(p + off4);
                    vb[k] = *(const uint2*)(p + off2);
                }
                int sn[4];    // prefetch next quad's indices before consuming
#pragma unroll
                for (int k = 0; k < 4; k++) sn[k] = lcsr[start + j + 4 + k];
#pragma unroll
                for (int k = 0; k < 4; k++) CONSUME(va[k], vb[k]);
#pragma unroll
                for (int k = 0; k < 4; k++) si[k] = sn[k];
            }
            {   // drain the in-flight quad
                uint4 va[4];
                uint2 vb[4];
#pragma unroll
                for (int k = 0; k < 4; k++) {
                    const u8* p = Xf8 + ((size_t)si[k] << 7);
                    va[k] = *(const uint4*)(p + off4);
                    vb[k] = *(const uint2*)(p + off2);
                }
#pragma unroll
                for (int k = 0; k < 4; k++) CONSUME(va[k], vb[k]);
                j += 4;
            }
        }
        for (; j < d; j++) {
            const u8* p = Xf8 + ((size_t)lcsr[start + j] << 7);
            uint4 va = *(const uint4*)(p + off4);
            uint2 vb = *(const uint2*)(p + off2);
            CONSUME(va, vb);
        }
#undef CONSUME

        float inv = 1.0f / fmaxf((float)d, 1.0f);
        u16* dl = sA + nl * 104;
        short8 o0v, o1v, o2v;
#pragma unroll
        for (int i = 0; i < 8; i++) {
            o0v[i] = (short)f2bf(acc[i] * inv);
            o1v[i] = (short)f2bf(acc[8 + i] * inv);
            o2v[i] = (short)f2bf(acc[16 + i] * inv);
        }
        *(short8*)(dl + q * 16) = o0v;          // channels 16q..16q+7
        *(short8*)(dl + q * 16 + 8) = o1v;      // channels 16q+8..16q+15
        *(short8*)(dl + 64 + q * 8) = o2v;      // channels 64+8q..64+8q+7
    }
    __syncthreads();

    // ---- dual MFMA GEMM ----
    const int lane = t & 63;
    const int w = t >> 6;
    const int quad = lane >> 4;
    const int l16 = lane & 15;
    const int r0 = row0 + w * 16;

    floatx4 acc6[6];
#pragma unroll
    for (int i = 0; i < 6; i++) acc6[i] = (floatx4){0.f, 0.f, 0.f, 0.f};

    {   // A-path: aggregated tile from LDS
        const u16* Ap = sA + (w * 16 + l16) * 104 + quad * 8;
        const u16* Wp = WTA + l16 * C + quad * 8;
#pragma unroll
        for (int ks = 0; ks < 3; ks++) {
            short8 a = *(const short8*)(Ap + ks * 32);
#pragma unroll
            for (int nt = 0; nt < 6; nt++) {
                short8 bb = *(const short8*)(Wp + nt * 16 * C + ks * 32);
                acc6[nt] = __builtin_amdgcn_mfma_f32_16x16x32_bf16(a, bb, acc6[nt], 0, 0, 0);
            }
        }
    }
    {   // Root path: own rows from global (bf16)
        int arow = r0 + l16;
        if (arow >= n) arow = n - 1;
        const u16* Xp = Xbf + (size_t)arow * C + quad * 8;
        const u16* Wp = WTR + l16 * C + quad * 8;
#pragma unroll
        for (int ks = 0; ks < 3; ks++) {
            short8 a = *(const short8*)(Xp + ks * 32);
#pragma unroll
            for (int nt = 0; nt < 6; nt++) {
                short8 bb = *(const short8*)(Wp + nt * 16 * C + ks * 32);
                acc6[nt] = __builtin_amdgcn_mfma_f32_16x16x32_bf16(a, bb, acc6[nt], 0, 0, 0);
            }
        }
    }

    // bias + relu in registers
#pragma unroll
    for (int nt = 0; nt < 6; nt++) {
        float bv = BIAS[nt * 16 + l16];
#pragma unroll
        for (int r = 0; r < 4; r++) {
            float v = acc6[nt][r] + bv;
            if (RELU) v = fmaxf(v, 0.f);
            acc6[nt][r] = v;
        }
    }
    __syncthreads();   // all sA (A-path) reads complete; safe to reuse

    const int nrow = min(64, n - row0);
    const int lr = w * 16 + quad * 4;          // this lane's tile rows lr..lr+3

    if constexpr (sizeof(OT) == 2) {
        // ---- bf16 output: stage 64x96 u16 (12 KB), write contiguous ----
        u16* so = sA;
#pragma unroll
        for (int nt = 0; nt < 6; nt++)
#pragma unroll
            for (int r = 0; r < 4; r++)
                so[(lr + r) * 96 + nt * 16 + l16] = f2bf(acc6[nt][r]);
        __syncthreads();
        {
            char* dstp = (char*)Y + (size_t)row0 * 192;
            int nbytes = nrow * 192;
            for (int ofs = t * 16; ofs < nbytes; ofs += 4096)
                *(uint4*)(dstp + ofs) = *(const uint4*)((const char*)sA + ofs);
        }
        if constexpr (WF8) {
            __syncthreads();
            u8* so8 = (u8*)sA;
#pragma unroll
            for (int nt = 0; nt < 6; nt++)
#pragma unroll
                for (int r = 0; r < 4; r++)
                    so8[(lr + r) * 96 + nt * 16 + l16] = f2fp8(acc6[nt][r]);
            __syncthreads();
            // padded-row fp8 writes: 6 x 16B chunks per row, row stride 128B
            char* dst8 = (char*)Yf8 + (size_t)row0 * F8S;
            int nchunks = nrow * 6;
            for (int cix = t; cix < nchunks; cix += 256) {
                int r = cix / 6, col = cix - r * 6;
                *(uint4*)(dst8 + (size_t)r * F8S + col * 16) =
                    *(const uint4*)((const char*)sA + r * 96 + col * 16);
            }
        }
    } else {
        // ---- fp32 output: two 32-row halves (12 KB each) ----
        float* sof = (float*)sA;
#pragma unroll
        for (int half = 0; half < 2; half++) {
            if (half) __syncthreads();
            if ((w >> 1) == half) {
#pragma unroll
                for (int nt = 0; nt < 6; nt++)
#pragma unroll
                    for (int r = 0; r < 4; r++)
                        sof[((w & 1) * 16 + quad * 4 + r) * 96 + nt * 16 + l16] = acc6[nt][r];
            }
            __syncthreads();
            int rbase = row0 + half * 32;
            int nr = n - rbase;
            nr = nr < 0 ? 0 : (nr > 32 ? 32 : nr);
            char* dstp = (char*)Y + (size_t)rbase * 384;
            int nbytes = nr * 384;
            for (int ofs = t * 16; ofs < nbytes; ofs += 4096)
                *(uint4*)(dstp + ofs) = *(const uint4*)((const char*)sA + ofs);
        }
    }
}

// ---------------------------------------------------------------------------
extern "C" void kernel_launch(void* const* d_in, const int* in_sizes, int n_in,
                              void* d_out, int out_size, void* d_ws, size_t ws_size,
                              hipStream_t stream) {
    const float* x   = (const float*)d_in[0];
    const int*   ei  = (const int*)d_in[1];
    const float* W1  = (const float*)d_in[2];
    const float* Wr1 = (const float*)d_in[3];
    const float* b1  = (const float*)d_in[4];
    const float* W2  = (const float*)d_in[5];
    const float* Wr2 = (const float*)d_in[6];
    const float* b2  = (const float*)d_in[7];
    float* out = (float*)d_out;

    const int N = in_sizes[0] / C;      // 50000
    const int E = in_sizes[1] / 2;      // 800000
    const int* src = ei;
    const int* dst = ei + E;

    const int DB   = (E + EB - 1) / EB;                 // 391
    const int NB   = (N + TB - 1) / TB;                 // 782
    const int n16  = N * C / 16;
    const int CX   = (n16 + 255) / 256;                 // 1172
    const size_t NBDB = ((size_t)NB * DB + 3) & ~(size_t)3;   // 16B-pad

    // Workspace layout (16B alignment for vector sections; fp8 128B rows)
    u32*  tabT = (u32*)d_ws;                             // NB*DB packed cnt|off
    u32*  stage = tabT + NBDB;                           // DB*EB
    u16*  xb   = (u16*)(stage + (size_t)DB * EB);        // N*C bf16
    u16*  h1b  = xb + (size_t)N * C;                     // N*C bf16
    u16*  wt   = h1b + (size_t)N * C;                    // 4*C*C bf16
    u16 *wt1 = wt, *wtr1 = wt + C * C, *wt2 = wt + 2 * C * C, *wtr2 = wt + 3 * C * C;
    u8*   xf8  = (u8*)(wt + 4 * C * C);                  // N*F8S fp8 (padded)
    u8*   h1f8 = xf8 + (size_t)N * F8S;                  // N*F8S fp8 (padded)

    sort_kernel<<<DB + CX + 4, 256, 0, stream>>>(src, dst, tabT, stage,
                                                 E, DB, NB,
                                                 x, xb, xf8, n16, CX,
                                                 W1, Wr1, W2, Wr2, wt1, wtr1, wt2, wtr2);

    layer_kernel<true, true, u16><<<NB, 256, 0, stream>>>(
        xb, xf8, tabT, stage, wt1, wtr1, b1, h1b, h1f8, N, DB);
    layer_kernel<false, false, float><<<NB, 256, 0, stream>>>(
        h1b, h1f8, tabT, stage, wt2, wtr2, b2, out, h1f8, N, DB);
}